// Round 7
// baseline (284.403 us; speedup 1.0000x reference)
//
#include <hip/hip_runtime.h>

#define EPS 1e-5f

constexpr int B = 8;
constexpr int V = 100000;
constexpr int F = 200000;
constexpr int U = 1024;
constexpr int T = 110000;

constexpr int TRB = (V + 255) / 256;       // transpose blocks (391)
constexpr int FNB = (F * 8 + 255) / 256;   // face-normal blocks (6250)
constexpr int CPB = (T + 255) / 256;       // corner-precompute blocks (430)

// adjacency-scan kernel geometry
constexpr int VPW = 512;                   // vertices owned per workgroup
constexpr int KWG = (V + VPW - 1) / VPW;   // 196 workgroups
constexpr int CAP = 28;                    // max faces/vertex kept; Poisson(6) tail @28 ~ 2e-12

struct Corner { int i0, i1, i2; float w0, w1, w2; };  // 24 B

// ---------------------------------------------------------------------------
// K1: transpose verts (B,V,3) -> vertsT (V,8) float4 (128 B padded rows so
// every downstream vertex gather is exactly one aligned cache line).
// ---------------------------------------------------------------------------
__global__ void k1_transpose(const float* __restrict__ verts,
                             float4* __restrict__ vertsT) {
    int v = blockIdx.x * blockDim.x + threadIdx.x;
    if (v >= V) return;
    float4 row[8];
#pragma unroll
    for (int b = 0; b < 8; ++b) {
        const float* p = verts + (size_t)b * V * 3 + (size_t)v * 3;
        row[b] = make_float4(p[0], p[1], p[2], 0.0f);
    }
    float4* dst = vertsT + (size_t)v * 8;
#pragma unroll
    for (int b = 0; b < 8; ++b) dst[b] = row[b];
}

// ---------------------------------------------------------------------------
// K2: two independent streaming phases fused (no atomics anywhere):
//   [0, FNB):       face normals per (f,b), each face computed once
//   [FNB, FNB+CPB): per-sample corner precompute (pixel side of grid-sample:
//                   clamped indices + fused bilinear*mask*bary weights)
// ---------------------------------------------------------------------------
__global__ void k2_fused(const int* __restrict__ vi,          // (F,3)
                         const float4* __restrict__ vertsT,   // (V,8)
                         float4* __restrict__ fn,             // (F,8)
                         const int* __restrict__ index_image, // (U,U,3)
                         const float* __restrict__ bary_image,// (U,U,3)
                         const float* __restrict__ vt,        // (T,2)
                         Corner* __restrict__ corners) {      // (T,4)
    int blk = blockIdx.x;

    if (blk < FNB) {
        // --- face normals ---
        int id = blk * 256 + threadIdx.x;
        if (id >= F * 8) return;
        int f = id >> 3;
        int b = id & 7;

        int i0 = vi[f * 3 + 0];
        int i1 = vi[f * 3 + 1];
        int i2 = vi[f * 3 + 2];

        float4 p0 = vertsT[(size_t)i0 * 8 + b];
        float4 p1 = vertsT[(size_t)i1 * 8 + b];
        float4 p2 = vertsT[(size_t)i2 * 8 + b];

        float e1x = p1.x - p0.x, e1y = p1.y - p0.y, e1z = p1.z - p0.z;
        float e2x = p2.x - p0.x, e2y = p2.y - p0.y, e2z = p2.z - p0.z;

        float nx = e1y * e2z - e1z * e2y;
        float ny = e1z * e2x - e1x * e2z;
        float nz = e1x * e2y - e1y * e2x;

        float norm = sqrtf(nx * nx + ny * ny + nz * nz);
        float inv = (norm < EPS) ? 1.0f : (1.0f / norm);
        fn[id] = make_float4(nx * inv, ny * inv, nz * inv, 0.0f);
        return;
    }

    // --- corner precompute (one thread per t) ---
    int t = (blk - FNB) * 256 + threadIdx.x;
    if (t >= T) return;

    float gx = vt[t * 2 + 0];
    float gy = vt[t * 2 + 1];
    float ix = gx * (float)U - 0.5f;   // ((gx*2-1)+1)*U*0.5 - 0.5
    float iy = gy * (float)U - 0.5f;

    float x0f = floorf(ix);
    float y0f = floorf(iy);
    int x0 = (int)x0f;
    int y0 = (int)y0f;
    float wx1 = ix - x0f, wx0 = 1.0f - wx1;
    float wy1 = iy - y0f, wy0 = 1.0f - wy1;

#pragma unroll
    for (int c = 0; c < 4; ++c) {
        int cy = c >> 1, cx = c & 1;
        int y = y0 + cy;
        int x = x0 + cx;
        Corner cr;
        if (x >= 0 && x < U && y >= 0 && y < U) {
            float w = (cy ? wy1 : wy0) * (cx ? wx1 : wx0);
            int pix = y * U + x;
            int i0 = index_image[pix * 3 + 0];
            int i1 = index_image[pix * 3 + 1];
            int i2 = index_image[pix * 3 + 2];
            float m = (i0 != -1 && i1 != -1 && i2 != -1) ? 1.0f : 0.0f;
            float wm = w * m;
            cr.i0 = min(max(i0, 0), V - 1);
            cr.i1 = min(max(i1, 0), V - 1);
            cr.i2 = min(max(i2, 0), V - 1);
            cr.w0 = wm * bary_image[pix * 3 + 0];
            cr.w1 = wm * bary_image[pix * 3 + 1];
            cr.w2 = wm * bary_image[pix * 3 + 2];
        } else {
            cr.i0 = 0; cr.i1 = 0; cr.i2 = 0;
            cr.w0 = 0.0f; cr.w1 = 0.0f; cr.w2 = 0.0f;
        }
        corners[t * 4 + c] = cr;
    }
}

// ---------------------------------------------------------------------------
// K3: adjacency-in-LDS + vertex-normal gather, NO device atomics.
// Each workgroup owns vertices [wg*VPW, wg*VPW+VPW): scans the entire vi
// array (int4 loads, L2-broadcast), keeps matching edges in LDS ELL rows
// (LDS atomics, ~3k matches/wg), then gathers fn (one aligned 128 B line per
// face per 8-lane batch group) and writes vn coalesced.
// ---------------------------------------------------------------------------
__global__ __launch_bounds__(512) void adj_gather(
        const int* __restrict__ vi,      // flat (3F)
        const float4* __restrict__ fn,   // (F,8)
        float4* __restrict__ vn) {       // (V,8)
    __shared__ int s_row[VPW * CAP];     // 57,344 B
    __shared__ int s_cnt[VPW];           //  2,048 B
    int tid = threadIdx.x;
    int v0 = blockIdx.x * VPW;

    for (int i = tid; i < VPW; i += 512) s_cnt[i] = 0;
    __syncthreads();

    // --- scan phase: all 600k edges, keep ours ---
    const int4* vi4 = (const int4*)vi;   // 3F = 600000, divisible by 4
    const int n4 = (3 * F) / 4;
    for (int m4 = tid; m4 < n4; m4 += 512) {
        int4 e = vi4[m4];
        int base = m4 * 4;
        int vv[4] = {e.x, e.y, e.z, e.w};
#pragma unroll
        for (int j = 0; j < 4; ++j) {
            unsigned d = (unsigned)(vv[j] - v0);
            if (d < (unsigned)VPW) {
                int pos = atomicAdd(&s_cnt[d], 1);
                if (pos < CAP) {
                    int face = (int)(__umulhi((unsigned)(base + j), 0xAAAAAAABu) >> 1); // (base+j)/3
                    s_row[d * CAP + pos] = face;
                }
            }
        }
    }
    __syncthreads();

    // --- gather phase: (vlocal, b) pairs; 8 lanes share v -> row broadcast,
    //     each fn gather covers one aligned 128 B line across the 8 lanes ---
    for (int id = tid; id < VPW * 8; id += 512) {
        int vl = id >> 3;
        int b = id & 7;
        int v = v0 + vl;
        if (v >= V) continue;
        int deg = min(s_cnt[vl], CAP);
        const int* row = s_row + vl * CAP;

        float ax = 0.0f, ay = 0.0f, az = 0.0f;
        for (int j = 0; j < deg; ++j) {
            int f = row[j];
            float4 n = fn[(size_t)f * 8 + b];
            ax += n.x; ay += n.y; az += n.z;
        }
        float nn = sqrtf(ax * ax + ay * ay + az * az);
        float inv = (nn < EPS) ? 1.0f : (1.0f / nn);
        vn[(size_t)v * 8 + b] = make_float4(ax * inv, ay * inv, az * inv, 0.0f);
    }
}

// ---------------------------------------------------------------------------
// K4: sample using precomputed corners. One thread per (t,b); pack reads
// broadcast across 8 lanes; 12 vn gathers, each one aligned 128 B line.
// ---------------------------------------------------------------------------
__global__ void sample_points(const float4* __restrict__ vn,      // (V,8)
                              const Corner* __restrict__ corners, // (T,4)
                              float4* __restrict__ vals) {        // (T,8)
    int id = blockIdx.x * blockDim.x + threadIdx.x;
    if (id >= T * 8) return;
    int t = id >> 3;
    int b = id & 7;

    float ax = 0.0f, ay = 0.0f, az = 0.0f;
#pragma unroll
    for (int c = 0; c < 4; ++c) {
        Corner cr = corners[t * 4 + c];
        float4 q0 = vn[(size_t)cr.i0 * 8 + b];
        float4 q1 = vn[(size_t)cr.i1 * 8 + b];
        float4 q2 = vn[(size_t)cr.i2 * 8 + b];
        ax += cr.w0 * q0.x + cr.w1 * q1.x + cr.w2 * q2.x;
        ay += cr.w0 * q0.y + cr.w1 * q1.y + cr.w2 * q2.y;
        az += cr.w0 * q0.z + cr.w1 * q1.z + cr.w2 * q2.z;
    }

    vals[id] = make_float4(ax, ay, az, 0.0f);
}

// ---------------------------------------------------------------------------
// K5: out[b,v,:] = mean over K=2 of vals[v2uv[v,k], b].
// ---------------------------------------------------------------------------
__global__ void gather_out(const float4* __restrict__ vals, // (T,8)
                           const int* __restrict__ v2uv,    // (V,2)
                           float* __restrict__ out) {       // (B,V,3)
    int id = blockIdx.x * blockDim.x + threadIdx.x;
    if (id >= V * 8) return;
    int v = id >> 3;
    int b = id & 7;

    int t0 = v2uv[v * 2 + 0];
    int t1 = v2uv[v * 2 + 1];
    float4 x = vals[(size_t)t0 * 8 + b];
    float4 y = vals[(size_t)t1 * 8 + b];

    float* o = out + (size_t)b * V * 3 + (size_t)v * 3;
    o[0] = 0.5f * (x.x + y.x);
    o[1] = 0.5f * (x.y + y.y);
    o[2] = 0.5f * (x.z + y.z);
}

extern "C" void kernel_launch(void* const* d_in, const int* in_sizes, int n_in,
                              void* d_out, int out_size, void* d_ws, size_t ws_size,
                              hipStream_t stream) {
    const float* verts   = (const float*)d_in[0]; // (B,V,3)
    const float* bary    = (const float*)d_in[1]; // (U,U,3)
    const float* vt      = (const float*)d_in[2]; // (T,2)
    const int*   vi      = (const int*)d_in[3];   // (F,3)
    const int*   idx_img = (const int*)d_in[4];   // (U,U,3)
    const int*   v2uv    = (const int*)d_in[5];   // (V,2)
    float* out = (float*)d_out;

    // Workspace (~49 MB), aliased by stream-ordered disjoint lifetimes:
    //   region A (12.8 MB): vertsT (K1 w, K2 r) -> vn (K3 w, K4 r)
    //   region B (25.6 MB): fn (K2 w, K3 r) -> vals 14.1 MB (K4 w, K5 r)
    //   region D (10.6 MB): corners (K2 w, K4 r)
    float4* vertsT  = (float4*)d_ws;
    float4* vn      = vertsT;                       // alias
    float4* fn      = vertsT + (size_t)V * 8;
    float4* vals    = fn;                           // alias
    Corner* corners = (Corner*)(fn + (size_t)F * 8);

    const int BLK = 256;
    k1_transpose<<<TRB, BLK, 0, stream>>>(verts, vertsT);
    k2_fused<<<FNB + CPB, BLK, 0, stream>>>(
        vi, vertsT, fn, idx_img, bary, vt, corners);
    adj_gather<<<KWG, 512, 0, stream>>>(vi, fn, vn);
    sample_points<<<(T * 8 + BLK - 1) / BLK, BLK, 0, stream>>>(vn, corners, vals);
    gather_out<<<(V * 8 + BLK - 1) / BLK, BLK, 0, stream>>>(vals, v2uv, out);
}

// Round 8
// 195.919 us; speedup vs baseline: 1.4516x; 1.4516x over previous
//
#include <hip/hip_runtime.h>

#define EPS 1e-5f

constexpr int B = 8;
constexpr int V = 100000;
constexpr int F = 200000;
constexpr int U = 1024;
constexpr int T = 110000;
constexpr int CAP = 24;                    // max faces/vertex; data max deg ~20

constexpr int TRB = (V + 255) / 256;       // transpose blocks (391)
constexpr int CZB = (V + 255) / 256;       // cnt-zero blocks (391)

// k2 interleaved-role geometry: 17-slot period = [1 ELL | 15 FN | 1 CP]
constexpr int N4   = (3 * F) / 4;               // 150000 int4 edges
constexpr int ELLB = (N4 + 255) / 256;          // 586 ELL blocks (1 int4/thread)
constexpr int FNB  = (F * 8 + 255) / 256;       // 6250 face-normal blocks
constexpr int CPB  = (T + 255) / 256;           // 430 corner blocks
constexpr int PERIODS = ELLB;                   // 586 (largest role stretch)
constexpr int K2N = PERIODS * 17;               // 9962 blocks; spares no-op

// ---------------------------------------------------------------------------
// K1: transpose verts (B,V,3) -> vertsT (V,8) float4 (128 B aligned rows)
//     + zero cnt (independent block range; replaces hipMemsetAsync).
// ---------------------------------------------------------------------------
__global__ void k1_pre(const float* __restrict__ verts,
                       float4* __restrict__ vertsT,
                       int* __restrict__ cnt) {
    int blk = blockIdx.x;
    if (blk < TRB) {
        int v = blk * 256 + threadIdx.x;
        if (v >= V) return;
        float4 row[8];
#pragma unroll
        for (int b = 0; b < 8; ++b) {
            const float* p = verts + (size_t)b * V * 3 + (size_t)v * 3;
            row[b] = make_float4(p[0], p[1], p[2], 0.0f);
        }
        float4* dst = vertsT + (size_t)v * 8;
#pragma unroll
        for (int b = 0; b < 8; ++b) dst[b] = row[b];
    } else {
        int i = (blk - TRB) * 256 + threadIdx.x;
        if (i < V) cnt[i] = 0;
    }
}

// ---------------------------------------------------------------------------
// K2: ELL build + face normals + corner precompute, ROLE-INTERLEAVED so the
// atomic-bound ELL waves co-reside with streaming waves on every CU
// (period of 17 blocks = 1 ELL + 15 FN + 1 CP).
// ---------------------------------------------------------------------------
__global__ void k2_fused(const int* __restrict__ vi,          // (F,3) flat
                         int* __restrict__ cnt,
                         int* __restrict__ ell,
                         const float4* __restrict__ vertsT,   // (V,8)
                         float4* __restrict__ fn,             // (F,8)
                         const int* __restrict__ index_image, // (U,U,3)
                         const float* __restrict__ bary_image,// (U,U,3)
                         const float* __restrict__ vt,        // (T,2)
                         int4* __restrict__ cI,               // (T,4)
                         float4* __restrict__ cW) {           // (T,4)
    int p = blockIdx.x / 17;
    int s = blockIdx.x % 17;

    if (s == 0) {
        // --- ELL build: 4 independent atomics in flight per lane ---
        int m4 = p * 256 + threadIdx.x;
        if (m4 >= N4) return;
        const int4* vi4 = (const int4*)vi;
        int4 e = vi4[m4];
        int base = m4 * 4;
        int vv[4] = {e.x, e.y, e.z, e.w};
#pragma unroll
        for (int j = 0; j < 4; ++j) {
            int v = vv[j];
            int pos = atomicAdd(&cnt[v], 1);
            if (pos < CAP) ell[v * CAP + pos] = (base + j) / 3;
        }
        return;
    }

    if (s <= 15) {
        // --- face normals, one thread per (f,b) ---
        int bid = p * 15 + (s - 1);
        if (bid >= FNB) return;
        int id = bid * 256 + threadIdx.x;
        if (id >= F * 8) return;
        int f = id >> 3;
        int b = id & 7;

        int i0 = vi[f * 3 + 0];
        int i1 = vi[f * 3 + 1];
        int i2 = vi[f * 3 + 2];

        float4 p0 = vertsT[(size_t)i0 * 8 + b];
        float4 p1 = vertsT[(size_t)i1 * 8 + b];
        float4 p2 = vertsT[(size_t)i2 * 8 + b];

        float e1x = p1.x - p0.x, e1y = p1.y - p0.y, e1z = p1.z - p0.z;
        float e2x = p2.x - p0.x, e2y = p2.y - p0.y, e2z = p2.z - p0.z;

        float nx = e1y * e2z - e1z * e2y;
        float ny = e1z * e2x - e1x * e2z;
        float nz = e1x * e2y - e1y * e2x;

        float norm = sqrtf(nx * nx + ny * ny + nz * nz);
        float inv = (norm < EPS) ? 1.0f : (1.0f / norm);
        fn[id] = make_float4(nx * inv, ny * inv, nz * inv, 0.0f);
        return;
    }

    // --- corner precompute (s == 16), one thread per t ---
    if (p >= CPB) return;
    int t = p * 256 + threadIdx.x;
    if (t >= T) return;

    float gx = vt[t * 2 + 0];
    float gy = vt[t * 2 + 1];
    float ix = gx * (float)U - 0.5f;   // ((gx*2-1)+1)*U*0.5 - 0.5
    float iy = gy * (float)U - 0.5f;

    float x0f = floorf(ix);
    float y0f = floorf(iy);
    int x0 = (int)x0f;
    int y0 = (int)y0f;
    float wx1 = ix - x0f, wx0 = 1.0f - wx1;
    float wy1 = iy - y0f, wy0 = 1.0f - wy1;

#pragma unroll
    for (int c = 0; c < 4; ++c) {
        int cy = c >> 1, cx = c & 1;
        int y = y0 + cy;
        int x = x0 + cx;
        int4 ci = make_int4(0, 0, 0, 0);
        float4 cw = make_float4(0.0f, 0.0f, 0.0f, 0.0f);
        if (x >= 0 && x < U && y >= 0 && y < U) {
            float w = (cy ? wy1 : wy0) * (cx ? wx1 : wx0);
            int pix = y * U + x;
            int i0 = index_image[pix * 3 + 0];
            int i1 = index_image[pix * 3 + 1];
            int i2 = index_image[pix * 3 + 2];
            float m = (i0 != -1 && i1 != -1 && i2 != -1) ? 1.0f : 0.0f;
            float wm = w * m;
            ci.x = min(max(i0, 0), V - 1);
            ci.y = min(max(i1, 0), V - 1);
            ci.z = min(max(i2, 0), V - 1);
            cw.x = wm * bary_image[pix * 3 + 0];
            cw.y = wm * bary_image[pix * 3 + 1];
            cw.z = wm * bary_image[pix * 3 + 2];
        }
        cI[t * 4 + c] = ci;
        cW[t * 4 + c] = cw;
    }
}

// ---------------------------------------------------------------------------
// K3: vertex-normal gather. One thread per (v,b); ell row broadcast across
// 8 lanes, each fn gather = one aligned 128 B line, 1-deep load chain.
// ---------------------------------------------------------------------------
__global__ void gather_vn(const float4* __restrict__ fn,  // (F,8)
                          const int* __restrict__ cnt,
                          const int* __restrict__ ell,
                          float4* __restrict__ vn) {       // (V,8)
    int id = blockIdx.x * blockDim.x + threadIdx.x;
    if (id >= V * 8) return;
    int v = id >> 3;
    int b = id & 7;

    int deg = min(cnt[v], CAP);
    const int* row = ell + (size_t)v * CAP;

    float ax = 0.0f, ay = 0.0f, az = 0.0f;
    for (int j = 0; j < deg; ++j) {
        int f = row[j];
        float4 n = fn[(size_t)f * 8 + b];
        ax += n.x; ay += n.y; az += n.z;
    }

    float n = sqrtf(ax * ax + ay * ay + az * az);
    float inv = (n < EPS) ? 1.0f : (1.0f / n);
    vn[id] = make_float4(ax * inv, ay * inv, az * inv, 0.0f);
}

// ---------------------------------------------------------------------------
// K4: sample with precomputed SoA corner pack. One thread per (t,b); pack
// reads broadcast across 8 lanes (2 vector loads per corner); 12 vn gathers,
// each one aligned 128 B line across the 8-lane group.
// ---------------------------------------------------------------------------
__global__ void sample_points(const float4* __restrict__ vn,  // (V,8)
                              const int4* __restrict__ cI,    // (T,4)
                              const float4* __restrict__ cW,  // (T,4)
                              float4* __restrict__ vals) {    // (T,8)
    int id = blockIdx.x * blockDim.x + threadIdx.x;
    if (id >= T * 8) return;
    int t = id >> 3;
    int b = id & 7;

    float ax = 0.0f, ay = 0.0f, az = 0.0f;
#pragma unroll
    for (int c = 0; c < 4; ++c) {
        int4 ci = cI[t * 4 + c];
        float4 cw = cW[t * 4 + c];
        float4 q0 = vn[(size_t)ci.x * 8 + b];
        float4 q1 = vn[(size_t)ci.y * 8 + b];
        float4 q2 = vn[(size_t)ci.z * 8 + b];
        ax += cw.x * q0.x + cw.y * q1.x + cw.z * q2.x;
        ay += cw.x * q0.y + cw.y * q1.y + cw.z * q2.y;
        az += cw.x * q0.z + cw.y * q1.z + cw.z * q2.z;
    }

    vals[id] = make_float4(ax, ay, az, 0.0f);
}

// ---------------------------------------------------------------------------
// K5: out[b,v,:] = mean over K=2 of vals[v2uv[v,k], b].
// ---------------------------------------------------------------------------
__global__ void gather_out(const float4* __restrict__ vals, // (T,8)
                           const int* __restrict__ v2uv,    // (V,2)
                           float* __restrict__ out) {       // (B,V,3)
    int id = blockIdx.x * blockDim.x + threadIdx.x;
    if (id >= V * 8) return;
    int v = id >> 3;
    int b = id & 7;

    int t0 = v2uv[v * 2 + 0];
    int t1 = v2uv[v * 2 + 1];
    float4 x = vals[(size_t)t0 * 8 + b];
    float4 y = vals[(size_t)t1 * 8 + b];

    float* o = out + (size_t)b * V * 3 + (size_t)v * 3;
    o[0] = 0.5f * (x.x + y.x);
    o[1] = 0.5f * (x.y + y.y);
    o[2] = 0.5f * (x.z + y.z);
}

extern "C" void kernel_launch(void* const* d_in, const int* in_sizes, int n_in,
                              void* d_out, int out_size, void* d_ws, size_t ws_size,
                              hipStream_t stream) {
    const float* verts   = (const float*)d_in[0]; // (B,V,3)
    const float* bary    = (const float*)d_in[1]; // (U,U,3)
    const float* vt      = (const float*)d_in[2]; // (T,2)
    const int*   vi      = (const int*)d_in[3];   // (F,3)
    const int*   idx_img = (const int*)d_in[4];   // (U,U,3)
    const int*   v2uv    = (const int*)d_in[5];   // (V,2)
    float* out = (float*)d_out;

    // Workspace (~62.5 MB), aliased by stream-ordered disjoint lifetimes:
    //   region A (12.8 MB): vertsT (K1 w, K2 r) -> vn (K3 w, K4 r)
    //   region B (25.6 MB): fn (K2 w, K3 r) -> vals 14.1 MB (K4 w, K5 r)
    //   region C (14.1 MB): cI + cW corner pack (K2 w, K4 r)
    //   region D (10.0 MB): cnt (V ints) + ell (V*CAP ints)
    float4* vertsT = (float4*)d_ws;
    float4* vn     = vertsT;                        // alias
    float4* fn     = vertsT + (size_t)V * 8;
    float4* vals   = fn;                            // alias
    int4*   cI     = (int4*)(fn + (size_t)F * 8);
    float4* cW     = (float4*)(cI + (size_t)T * 4);
    int*    cnt    = (int*)(cW + (size_t)T * 4);
    int*    ell    = cnt + V;

    const int BLK = 256;
    k1_pre<<<TRB + CZB, BLK, 0, stream>>>(verts, vertsT, cnt);
    k2_fused<<<K2N, BLK, 0, stream>>>(
        vi, cnt, ell, vertsT, fn, idx_img, bary, vt, cI, cW);
    gather_vn<<<(V * 8 + BLK - 1) / BLK, BLK, 0, stream>>>(fn, cnt, ell, vn);
    sample_points<<<(T * 8 + BLK - 1) / BLK, BLK, 0, stream>>>(vn, cI, cW, vals);
    gather_out<<<(V * 8 + BLK - 1) / BLK, BLK, 0, stream>>>(vals, v2uv, out);
}